// Round 8
// baseline (979.816 us; speedup 1.0000x reference)
//
#include <hip/hip_runtime.h>
#include <math.h>

#define H_DIM 1024
#define SEG_LEN 18
#define N_SEG 32
#define QUOTA 9
#define GAP_THR 8.0e-4f

typedef _Float16 half8 __attribute__((ext_vector_type(8)));
typedef _Float16 half4 __attribute__((ext_vector_type(4)));
typedef float f32x4 __attribute__((ext_vector_type(4)));
typedef float f32x16 __attribute__((ext_vector_type(16)));

__device__ __forceinline__ void gload_lds16(const void* g, void* l) {
    __builtin_amdgcn_global_load_lds((const __attribute__((address_space(1))) uint32_t*)g,
                                     (__attribute__((address_space(3))) uint32_t*)l,
                                     16, 0, 0);
}

__device__ __forceinline__ float gelu_exact(float h) {
    return 0.5f * h * (1.0f + erff(h * 0.70710678118654752f));
}

__device__ __forceinline__ half8 cvt8(float4 a, float4 b) {
    half8 h;
    h[0] = (_Float16)a.x; h[1] = (_Float16)a.y; h[2] = (_Float16)a.z; h[3] = (_Float16)a.w;
    h[4] = (_Float16)b.x; h[5] = (_Float16)b.y; h[6] = (_Float16)b.z; h[7] = (_Float16)b.w;
    return h;
}

// ---- pack W1 [512][1024] fp32 into two layouts ----
// B32 (2 MB): 32x32x16-frag order, 2 exact-split fp16 planes:
//   half-off = kt*32768 + nb*16384 + ksub*4096 + nf*512 + (hi*32+nlo)*8 + j  (+8192 plane1)
// B16 (1 MB): 16x16x32-frag order, plane-0 only:
//   half-off = (ks*32 + nf16)*512 + lane*8 + j
__global__ void pack_w1_kernel(const float* __restrict__ W1,
                               _Float16* __restrict__ B32,
                               _Float16* __restrict__ B16) {
    const int bid = blockIdx.x, t = threadIdx.x;
    if (bid < 256) {
        int tid = bid * 256 + t;                 // 512 n x 128 k-octets
        int q = tid & 127, n = tid >> 7;
        int kt = q >> 2, ksub = (q >> 1) & 1, hi = q & 1;
        int nb = n >> 8, nf = (n >> 5) & 7, nlo = n & 31;
        const float* src = W1 + (size_t)n * H_DIM + q * 8;
        float4 v0 = *(const float4*)src, v1 = *(const float4*)(src + 4);
        float xs[8] = {v0.x, v0.y, v0.z, v0.w, v1.x, v1.y, v1.z, v1.w};
        half8 h0, h1;
#pragma unroll
        for (int j = 0; j < 8; ++j) {
            _Float16 a = (_Float16)xs[j];
            float r = xs[j] - (float)a;
            h0[j] = a;
            h1[j] = (_Float16)(r * 2048.0f);
        }
        size_t base = (size_t)kt * 32768 + nb * 16384 + ksub * 4096 + nf * 512
                    + (size_t)(hi * 32 + nlo) * 8;
        *(half8*)(B32 + base) = h0;
        *(half8*)(B32 + base + 8192) = h1;
    } else {
        int tid = (bid - 256) * 256 + t;
        int lane = tid & 63, nf = (tid >> 6) & 31, ks = tid >> 11;
        int n = nf * 16 + (lane & 15), k0 = ks * 32 + (lane >> 4) * 8;
        const float* src = W1 + (size_t)n * H_DIM + k0;
        float4 v0 = *(const float4*)src, v1 = *(const float4*)(src + 4);
        float xs[8] = {v0.x, v0.y, v0.z, v0.w, v1.x, v1.y, v1.z, v1.w};
        half8 h0;
#pragma unroll
        for (int j = 0; j < 8; ++j) h0[j] = (_Float16)xs[j];
        *(half8*)(B16 + ((size_t)(ks * 32 + nf)) * 512 + lane * 8) = h0;
    }
}

// ---- stage-1 scorer: barrier-free, LDS-free direct-fragment streaming ----
// 64 rows x 256 cols (nb half) per block; 4 waves each 64x64; both operands
// loaded straight from global in fragment order, reg-double-buffered.
__global__ __launch_bounds__(256, 3)
void stage1_kernel(const float* __restrict__ X, const _Float16* __restrict__ B16,
                   const float* __restrict__ b1, const float* __restrict__ W2,
                   float* __restrict__ sparts, int tot) {
    __shared__ float red[4 * 64 * 17];
    const int t = threadIdx.x, w = t >> 6, lane = t & 63;

    // bijective XCD-chunked swizzle (nwg % 8 == 0): the 2 nb-blocks of one
    // m-row are logically adjacent -> same XCD -> L2 serves the X re-read.
    const int nwg = (int)gridDim.x, chunk = nwg >> 3;
    const int logical = ((int)blockIdx.x & 7) * chunk + ((int)blockIdx.x >> 3);
    const int nb = logical & 1;
    const size_t m0 = (size_t)(logical >> 1) * 64;

    // A direct: lane -> row (lane&15), k-octet (lane>>4); 16 full 128B lines/frag
    const float* aBase = X + (m0 + (lane & 15)) * H_DIM + (lane >> 4) * 8;
    // B direct: frag (ks, w*4+j) = 64 lanes x 16 B contiguous (L2-resident)
    const _Float16* bBase = B16 + ((size_t)nb * 16 + w * 4) * 512 + lane * 8;

    f32x4 acc[4][4] = {};
    float4 ar[8];            // raw A (current ks), frag mf -> ar[2mf], ar[2mf+1]
    half8 bcur[4], bnxt[4];

#pragma unroll
    for (int mf = 0; mf < 4; ++mf) {
        ar[mf * 2]     = *(const float4*)(aBase + mf * 16 * H_DIM);
        ar[mf * 2 + 1] = *(const float4*)(aBase + mf * 16 * H_DIM + 4);
    }
#pragma unroll
    for (int j = 0; j < 4; ++j) bcur[j] = *(const half8*)(bBase + (size_t)j * 512);

    for (int ks = 0; ks < 32; ++ks) {
        half8 ah[4];
#pragma unroll
        for (int mf = 0; mf < 4; ++mf) ah[mf] = cvt8(ar[mf * 2], ar[mf * 2 + 1]);

        if (ks < 31) {  // prefetch next K-step while MFMAing this one
#pragma unroll
            for (int mf = 0; mf < 4; ++mf) {
                ar[mf * 2]     = *(const float4*)(aBase + mf * 16 * H_DIM + (ks + 1) * 32);
                ar[mf * 2 + 1] = *(const float4*)(aBase + mf * 16 * H_DIM + (ks + 1) * 32 + 4);
            }
#pragma unroll
            for (int j = 0; j < 4; ++j)
                bnxt[j] = *(const half8*)(bBase + ((size_t)(ks + 1) * 32 + j) * 512);
        }

        __builtin_amdgcn_s_setprio(1);
#pragma unroll
        for (int mf = 0; mf < 4; ++mf)
#pragma unroll
            for (int nf = 0; nf < 4; ++nf)
                acc[mf][nf] = __builtin_amdgcn_mfma_f32_16x16x32_f16(ah[mf], bcur[nf], acc[mf][nf], 0, 0, 0);
        __builtin_amdgcn_s_setprio(0);

#pragma unroll
        for (int j = 0; j < 4; ++j) bcur[j] = bnxt[j];
    }

    // epilogue: h = acc + b1; gelu; *W2; reduce 256 cols -> partial scores
    const int hi = lane >> 4, lc = lane & 15;
    float b1v[4], w2v[4];
#pragma unroll
    for (int nf = 0; nf < 4; ++nf) {
        int c = nb * 256 + w * 64 + nf * 16 + lc;
        b1v[nf] = b1[c];
        w2v[nf] = W2[c];
    }
#pragma unroll
    for (int mf = 0; mf < 4; ++mf) {
#pragma unroll
        for (int i = 0; i < 4; ++i) {
            float s = 0.f;
#pragma unroll
            for (int nf = 0; nf < 4; ++nf) {
                float h = acc[mf][nf][i] + b1v[nf];
                s = fmaf(gelu_exact(h), w2v[nf], s);
            }
            red[(w * 64 + mf * 16 + hi * 4 + i) * 17 + lc] = s;
        }
    }
    __syncthreads();
    if (t < 64) {
        float s = 0.f;
#pragma unroll
        for (int ww = 0; ww < 4; ++ww)
#pragma unroll
            for (int c = 0; c < 16; ++c) s += red[(ww * 64 + t) * 17 + c];
        sparts[(size_t)nb * tot + m0 + t] = s;
    }
}

// ---- flag + provisional select from screen scores ----
__global__ void flag_select_kernel(const float* __restrict__ sparts, int tot,
                                   int* __restrict__ sel_buf,
                                   int* __restrict__ flag_list,
                                   int* __restrict__ counter, int N, int nseg_tot) {
    int seg = blockIdx.x * 256 + threadIdx.x;
    if (seg >= nseg_tot) return;
    int b = seg >> 5, s = seg & 31;
    size_t base = (size_t)b * N + s * SEG_LEN;
    float sc[SEG_LEN];
#pragma unroll
    for (int j = 0; j < SEG_LEN; ++j) sc[j] = sparts[base + j] + sparts[base + j + tot];
    unsigned mask = 0;
    float best9 = 0.f;
    for (int it = 0; it < QUOTA; ++it) {
        float best = 0.f; int bi = 0; bool found = false;
        for (int i = 0; i < SEG_LEN; ++i) if (!((mask >> i) & 1u)) {
            if (!found || sc[i] > best) { best = sc[i]; bi = i; found = true; }
        }
        mask |= 1u << bi;
        best9 = best;
    }
    float best10 = 0.f; bool f10 = false;
    for (int i = 0; i < SEG_LEN; ++i) if (!((mask >> i) & 1u)) {
        if (!f10 || sc[i] > best10) { best10 = sc[i]; f10 = true; }
    }
    if (best9 - best10 > GAP_THR) {
        int c = 0;
        for (int i = 0; i < SEG_LEN; ++i)
            if ((mask >> i) & 1u) sel_buf[(size_t)seg * QUOTA + (c++)] = i;
    } else {
        int p = atomicAdd(counter, 1);
        flag_list[p] = seg;
    }
}

// ---- exact recheck (fp16-split 3-pass, proven numerics) of flagged segments ----
// block = 3 flagged segments (54 rows padded to 64) x 512 cols, 8 waves 64x64.
// LDS: A 8 KB + B 64 KB = 72 KB; epilogue red[8][64][33]+sx overlays.
__global__ __launch_bounds__(512, 2)
void recheck_kernel(const float* __restrict__ X, const _Float16* __restrict__ B32,
                    const float* __restrict__ b1, const float* __restrict__ W2,
                    const int* __restrict__ flag_list, const int* __restrict__ counter,
                    int* __restrict__ sel_buf, int N) {
    const int count = *counter;
    const int jb = blockIdx.x;
    if (jb * 3 >= count) return;
    __shared__ __align__(16) char smem[73728];
    const int t = threadIdx.x, w = t >> 6, lane = t & 63;

    // A staging: row r_ = t>>3 (0..63), 4-float k-quad kq8 = t&7 (uniform all waves)
    const int r_ = t >> 3, kq8 = t & 7;
    int q = r_ / 18, rr = r_ % 18;
    if (r_ >= 54) { q = 2; rr = 0; }          // padding rows: harmless duplicates
    int li = jb * 3 + q; if (li >= count) li = count - 1;
    const int sg = flag_list[li];
    const float* aRow = X + ((size_t)(sg >> 5) * N + (sg & 31) * SEG_LEN + rr) * H_DIM + kq8 * 4;
    const int rg = r_ >> 5, aks = kq8 >> 2, ahi = (kq8 >> 1) & 1;
    const int aoff = (rg * 2 + aks) * 1024 + (ahi * 32 + (r_ & 31)) * 16 + (kq8 & 1) * 8;

    f32x16 acc1[2][2] = {};
    f32x16 acc2[2][2] = {};
    float4 av = *(const float4*)aRow;

    for (int kt = 0; kt < 32; ++kt) {
        // stage B(kt): 64 KB linear from B32
#pragma unroll
        for (int r8 = 0; r8 < 8; ++r8) {
            int idx = r8 * 512 + t;
            gload_lds16(B32 + (size_t)kt * 32768 + (size_t)idx * 8,
                        smem + 8192 + (size_t)idx * 16);
        }
        {   // convert+write A(kt): waits av (older than the 8 gloads)
            float xs[4] = {av.x, av.y, av.z, av.w};
            half4 h0, h1;
#pragma unroll
            for (int j = 0; j < 4; ++j) {
                _Float16 a = (_Float16)xs[j];
                float r = xs[j] - (float)a;
                h0[j] = a;
                h1[j] = (_Float16)(r * 2048.0f);
            }
            *(half4*)(smem + aoff) = h0;
            *(half4*)(smem + 4096 + aoff) = h1;
        }
        int ktn = kt < 31 ? kt + 1 : 31;       // clamped re-read keeps vmcnt uniform
        av = *(const float4*)(aRow + ktn * 32);
        asm volatile("s_waitcnt vmcnt(1) lgkmcnt(0)" ::: "memory");
        __builtin_amdgcn_sched_barrier(0);
        __builtin_amdgcn_s_barrier();

        half8 a0[4], a1[4], b0[4], b1f[4];
#pragma unroll
        for (int mf = 0; mf < 2; ++mf)
#pragma unroll
            for (int ks2 = 0; ks2 < 2; ++ks2) {
                a0[mf * 2 + ks2] = *(const half8*)(smem + (mf * 2 + ks2) * 1024 + lane * 16);
                a1[mf * 2 + ks2] = *(const half8*)(smem + 4096 + (mf * 2 + ks2) * 1024 + lane * 16);
            }
        const char* bb = smem + 8192 + (w >> 2) * 32768;
#pragma unroll
        for (int nfl = 0; nfl < 2; ++nfl)
#pragma unroll
            for (int ks2 = 0; ks2 < 2; ++ks2) {
                b0[nfl * 2 + ks2]  = *(const half8*)(bb + ks2 * 8192 + ((w & 3) * 2 + nfl) * 1024 + lane * 16);
                b1f[nfl * 2 + ks2] = *(const half8*)(bb + 16384 + ks2 * 8192 + ((w & 3) * 2 + nfl) * 1024 + lane * 16);
            }
        __builtin_amdgcn_s_setprio(1);
#pragma unroll
        for (int mf = 0; mf < 2; ++mf)
#pragma unroll
            for (int nfl = 0; nfl < 2; ++nfl)
#pragma unroll
                for (int ks2 = 0; ks2 < 2; ++ks2)
                    acc1[mf][nfl] = __builtin_amdgcn_mfma_f32_32x32x16_f16(
                        a0[mf * 2 + ks2], b0[nfl * 2 + ks2], acc1[mf][nfl], 0, 0, 0);
#pragma unroll
        for (int mf = 0; mf < 2; ++mf)
#pragma unroll
            for (int nfl = 0; nfl < 2; ++nfl)
#pragma unroll
                for (int ks2 = 0; ks2 < 2; ++ks2)
                    acc2[mf][nfl] = __builtin_amdgcn_mfma_f32_32x32x16_f16(
                        a0[mf * 2 + ks2], b1f[nfl * 2 + ks2], acc2[mf][nfl], 0, 0, 0);
#pragma unroll
        for (int mf = 0; mf < 2; ++mf)
#pragma unroll
            for (int nfl = 0; nfl < 2; ++nfl)
#pragma unroll
                for (int ks2 = 0; ks2 < 2; ++ks2)
                    acc2[mf][nfl] = __builtin_amdgcn_mfma_f32_32x32x16_f16(
                        a1[mf * 2 + ks2], b0[nfl * 2 + ks2], acc2[mf][nfl], 0, 0, 0);
        __builtin_amdgcn_s_setprio(0);
        __builtin_amdgcn_s_barrier();          // all reads done before next staging
    }

    // epilogue: exact scores, then in-block top-9 per flagged segment
    __syncthreads();
    float* red = (float*)smem;                 // [8][64][33]
    float b1v[2], w2v[2];
#pragma unroll
    for (int nfl = 0; nfl < 2; ++nfl) {
        int c = (w >> 2) * 256 + ((w & 3) * 2 + nfl) * 32 + (lane & 31);
        b1v[nfl] = b1[c];
        w2v[nfl] = W2[c];
    }
#pragma unroll
    for (int mf = 0; mf < 2; ++mf)
#pragma unroll
        for (int i = 0; i < 16; ++i) {
            float s = 0.f;
#pragma unroll
            for (int nfl = 0; nfl < 2; ++nfl) {
                float h = acc1[mf][nfl][i] + acc2[mf][nfl][i] * (1.0f / 2048.0f) + b1v[nfl];
                s = fmaf(gelu_exact(h), w2v[nfl], s);
            }
            int row = mf * 32 + (i & 3) + 8 * (i >> 2) + 4 * (lane >> 5);
            red[(w * 64 + row) * 33 + (lane & 31)] = s;
        }
    __syncthreads();
    float* sx = (float*)(smem + 67584);        // [64]
    if (t < 64) {
        float s = 0.f;
        for (int ww = 0; ww < 8; ++ww)
#pragma unroll
            for (int lc = 0; lc < 32; ++lc) s += red[(ww * 64 + t) * 33 + lc];
        sx[t] = s;
    }
    __syncthreads();
    if (t < 3 && jb * 3 + t < count) {
        int sg2 = flag_list[jb * 3 + t];
        const float* sv = sx + t * SEG_LEN;
        unsigned mask = 0;
        for (int it = 0; it < QUOTA; ++it) {
            float best = 0.f; int bi = 0; bool found = false;
            for (int i = 0; i < SEG_LEN; ++i) if (!((mask >> i) & 1u)) {
                if (!found || sv[i] > best) { best = sv[i]; bi = i; found = true; }
            }
            mask |= 1u << bi;
        }
        int c = 0;
        for (int i = 0; i < SEG_LEN; ++i)
            if ((mask >> i) & 1u) sel_buf[(size_t)sg2 * QUOTA + (c++)] = i;
    }
}

// ---- final gather of selected rows ----
__global__ void gather_kernel(const float* __restrict__ X, const int* __restrict__ sel_buf,
                              float* __restrict__ out, int N) {
    const int seg = blockIdx.x, b = blockIdx.y, t = threadIdx.x;
    const int* sel = sel_buf + ((size_t)b * N_SEG + seg) * QUOTA;
    const float4* xb = (const float4*)X + ((size_t)b * N + seg * SEG_LEN) * (H_DIM / 4);
    float4* ob = (float4*)out + ((size_t)b * N_SEG * QUOTA + seg * QUOTA) * (H_DIM / 4);
#pragma unroll
    for (int j = 0; j < QUOTA; ++j) {
        int r = sel[j];
        ob[(size_t)j * (H_DIM / 4) + t] = xb[(size_t)r * (H_DIM / 4) + t];
    }
}

extern "C" void kernel_launch(void* const* d_in, const int* in_sizes, int n_in,
                              void* d_out, int out_size, void* d_ws, size_t ws_size,
                              hipStream_t stream) {
    const float* X  = (const float*)d_in[0];
    const float* W1 = (const float*)d_in[1];
    const float* b1 = (const float*)d_in[2];
    const float* W2 = (const float*)d_in[3];
    // d_in[4] (b2): constant shift, selection-invariant; d_in[5]: quota via out_size
    float* out = (float*)d_out;

    const int Hh = in_sizes[2];                        // 512
    const int H  = Hh * 2;                             // 1024
    const long long TOT = (long long)in_sizes[0] / H;  // 147456 tokens
    const int B = 256;
    const int N = (int)(TOT / B);                      // 576
    const int nseg_tot = B * N_SEG;                    // 8192

    char* ws = (char*)d_ws;
    _Float16* B32 = (_Float16*)(ws + 0);               // 2 MB
    _Float16* B16 = (_Float16*)(ws + 2097152);         // 1 MB
    float* sparts = (float*)(ws + 3145728);            // 2*TOT f32
    int* sel_buf  = (int*)(ws + 4325376);              // 8192*9
    int* flag_list= (int*)(ws + 4620288);              // 8192
    int* counter  = (int*)(ws + 4653056);

    hipMemsetAsync(counter, 0, 16, stream);

    hipLaunchKernelGGL(pack_w1_kernel, dim3(512), dim3(256), 0, stream, W1, B32, B16);

    const int nwg = (int)(TOT / 64) * 2;               // 4608, divisible by 8
    hipLaunchKernelGGL(stage1_kernel, dim3(nwg), dim3(256), 0, stream,
                       X, B16, b1, W2, sparts, (int)TOT);

    hipLaunchKernelGGL(flag_select_kernel, dim3((nseg_tot + 255) / 256), dim3(256), 0, stream,
                       sparts, (int)TOT, sel_buf, flag_list, counter, N, nseg_tot);

    hipLaunchKernelGGL(recheck_kernel, dim3((nseg_tot + 2) / 3), dim3(512), 0, stream,
                       X, B32, b1, W2, flag_list, counter, sel_buf, N);

    hipLaunchKernelGGL(gather_kernel, dim3(N_SEG, B), dim3(256), 0, stream,
                       X, sel_buf, out, N);
}

// Round 9
// 573.715 us; speedup vs baseline: 1.7078x; 1.7078x over previous
//
#include <hip/hip_runtime.h>
#include <math.h>

#define H_DIM 1024
#define SEG_LEN 18
#define N_SEG 32
#define QUOTA 9
#define GAP_THR 8.0e-4f

typedef _Float16 half8 __attribute__((ext_vector_type(8)));
typedef _Float16 half4 __attribute__((ext_vector_type(4)));
typedef float f32x4 __attribute__((ext_vector_type(4)));
typedef float f32x16 __attribute__((ext_vector_type(16)));

__device__ __forceinline__ void gload_lds16(const void* g, void* l) {
    __builtin_amdgcn_global_load_lds((const __attribute__((address_space(1))) uint32_t*)g,
                                     (__attribute__((address_space(3))) uint32_t*)l,
                                     16, 0, 0);
}

__device__ __forceinline__ float gelu_exact(float h) {
    return 0.5f * h * (1.0f + erff(h * 0.70710678118654752f));
}

// ---- pack W1 [512][1024] fp32 into two layouts ----
// B32 (2 MB): 32x32x16-frag order, 2 exact-split fp16 planes (recheck kernel).
// B16 (1 MB): 16x16x32-frag order, plane-0 only (screen kernel):
//   half-off = (ks*32 + nf16)*512 + lane*8 + j
__global__ void pack_w1_kernel(const float* __restrict__ W1,
                               _Float16* __restrict__ B32,
                               _Float16* __restrict__ B16) {
    const int bid = blockIdx.x, t = threadIdx.x;
    if (bid < 256) {
        int tid = bid * 256 + t;                 // 512 n x 128 k-octets
        int q = tid & 127, n = tid >> 7;
        int kt = q >> 2, ksub = (q >> 1) & 1, hi = q & 1;
        int nb = n >> 8, nf = (n >> 5) & 7, nlo = n & 31;
        const float* src = W1 + (size_t)n * H_DIM + q * 8;
        float4 v0 = *(const float4*)src, v1 = *(const float4*)(src + 4);
        float xs[8] = {v0.x, v0.y, v0.z, v0.w, v1.x, v1.y, v1.z, v1.w};
        half8 h0, h1;
#pragma unroll
        for (int j = 0; j < 8; ++j) {
            _Float16 a = (_Float16)xs[j];
            float r = xs[j] - (float)a;
            h0[j] = a;
            h1[j] = (_Float16)(r * 2048.0f);
        }
        size_t base = (size_t)kt * 32768 + nb * 16384 + ksub * 4096 + nf * 512
                    + (size_t)(hi * 32 + nlo) * 8;
        *(half8*)(B32 + base) = h0;
        *(half8*)(B32 + base + 8192) = h1;
    } else {
        int tid = (bid - 256) * 256 + t;
        int lane = tid & 63, nf = (tid >> 6) & 31, ks = tid >> 11;
        int n = nf * 16 + (lane & 15), k0 = ks * 32 + (lane >> 4) * 8;
        const float* src = W1 + (size_t)n * H_DIM + k0;
        float4 v0 = *(const float4*)src, v1 = *(const float4*)(src + 4);
        float xs[8] = {v0.x, v0.y, v0.z, v0.w, v1.x, v1.y, v1.z, v1.w};
        half8 h0;
#pragma unroll
        for (int j = 0; j < 8; ++j) h0[j] = (_Float16)xs[j];
        *(half8*)(B16 + ((size_t)(ks * 32 + nf)) * 512 + lane * 8) = h0;
    }
}

// ---- stage-1 scorer: R7 structure with BK=64 (halved barrier count) ----
// 64 rows x 256 cols (nb half), 4 waves of 64x64; dbuf; counted vmcnt.
// LDS per buf: As 8 KB (fp16 frag-packed, 64 k) + Bs 32 KB -> 80 KB total.
//   As frag (ksub,mf) at buf*40960 + (ksub*4+mf)*1024 + slot*16
//   Bs frag (ksub,nf16) at buf*40960 + 8192 + (ksub*16+nf)*1024 + slot*16
__global__ __launch_bounds__(256, 2)
void stage1_kernel(const float* __restrict__ X, const _Float16* __restrict__ B16,
                   const float* __restrict__ b1, const float* __restrict__ W2,
                   float* __restrict__ sparts, int tot) {
    __shared__ __align__(16) char smem[81920];
    const int t = threadIdx.x, w = t >> 6, lane = t & 63;
    const int nb = blockIdx.y;
    const size_t m0 = (size_t)blockIdx.x * 64;

    // A staging: thread t -> row t>>2 (0..63), k-octets c0=(t&3)*2 and c0+1
    const int r_ = t >> 2;
    const int c0 = (t & 3) * 2;
    const float* aptr = X + (m0 + r_) * H_DIM + c0 * 8;
    // write offsets for the two converted half8s (frag ksub=c>>2, lanepart c&3)
    const int mfw = r_ >> 4;
    const int wo0 = ((c0 >> 2) * 4 + mfw) * 1024 + ((r_ & 15) + ((c0 & 3) << 4)) * 16;
    const int c1 = c0 + 1;
    const int wo1 = ((c1 >> 2) * 4 + mfw) * 1024 + ((r_ & 15) + ((c1 & 3) << 4)) * 16;

    f32x4 acc[4][4] = {};
    float4 av0, av1, av2, av3;

#define S1_ALOAD(kt)                                                            \
    do {                                                                        \
        av0 = *(const float4*)(aptr + (kt) * 64);                               \
        av1 = *(const float4*)(aptr + (kt) * 64 + 4);                           \
        av2 = *(const float4*)(aptr + (kt) * 64 + 8);                           \
        av3 = *(const float4*)(aptr + (kt) * 64 + 12);                          \
    } while (0)

#define S1_CONVERT(buf)                                                         \
    do {                                                                        \
        float x0[8] = {av0.x, av0.y, av0.z, av0.w, av1.x, av1.y, av1.z, av1.w}; \
        float x1[8] = {av2.x, av2.y, av2.z, av2.w, av3.x, av3.y, av3.z, av3.w}; \
        half8 h0, h1;                                                           \
        _Pragma("unroll") for (int j = 0; j < 8; ++j) {                         \
            h0[j] = (_Float16)x0[j];                                            \
            h1[j] = (_Float16)x1[j];                                            \
        }                                                                       \
        *(half8*)(smem + (buf) * 40960 + wo0) = h0;                             \
        *(half8*)(smem + (buf) * 40960 + wo1) = h1;                             \
    } while (0)

    // stage 32 KB of B for K64-tile kt (= two 32-k slabs of B16)
#define S1_STAGE(kt, buf)                                                       \
    do {                                                                        \
        char* dst = smem + (buf) * 40960 + 8192;                                \
        _Pragma("unroll") for (int r8 = 0; r8 < 8; ++r8) {                      \
            int idx = r8 * 256 + t;             /* 0..2047 16B chunks */        \
            int ksub = idx >> 10, rem = idx & 1023;                             \
            gload_lds16(B16 + ((size_t)((2 * (kt) + ksub) * 32 + nb * 16        \
                                        + (rem >> 6))) * 512 + (rem & 63) * 8,  \
                        dst + idx * 16);                                        \
        }                                                                       \
    } while (0)

    // ---- prologue ----
    S1_ALOAD(0);
    S1_STAGE(0, 0);
    S1_CONVERT(0);                 // compiler waits the 4 A-loads; B flies
    __builtin_amdgcn_sched_barrier(0);
    S1_ALOAD(1);
    __builtin_amdgcn_sched_barrier(0);
    asm volatile("s_waitcnt vmcnt(4) lgkmcnt(0)" ::: "memory");
    __builtin_amdgcn_sched_barrier(0);
    __builtin_amdgcn_s_barrier();

    int cur = 0;
    for (int kt = 0; kt < 16; ++kt) {
        const int nxt = cur ^ 1;
        if (kt < 15) {
            S1_STAGE(kt + 1, nxt);           // 8 gloads (newest)
            __builtin_amdgcn_sched_barrier(0);
            S1_CONVERT(nxt);                 // consumes av = A(kt+1), older
            if (kt < 14) S1_ALOAD(kt + 2);   // 4 loads stay in flight
            __builtin_amdgcn_sched_barrier(0);
        }
        half8 aA[2][4], bA[2][4];
#pragma unroll
        for (int ksub = 0; ksub < 2; ++ksub) {
#pragma unroll
            for (int mf = 0; mf < 4; ++mf)
                aA[ksub][mf] = *(const half8*)(smem + cur * 40960 + (ksub * 4 + mf) * 1024 + lane * 16);
#pragma unroll
            for (int nf = 0; nf < 4; ++nf)
                bA[ksub][nf] = *(const half8*)(smem + cur * 40960 + 8192 + (ksub * 16 + w * 4 + nf) * 1024 + lane * 16);
        }

        __builtin_amdgcn_s_setprio(1);
#pragma unroll
        for (int ksub = 0; ksub < 2; ++ksub)
#pragma unroll
            for (int mf = 0; mf < 4; ++mf)
#pragma unroll
                for (int nf = 0; nf < 4; ++nf)
                    acc[mf][nf] = __builtin_amdgcn_mfma_f32_16x16x32_f16(
                        aA[ksub][mf], bA[ksub][nf], acc[mf][nf], 0, 0, 0);
        __builtin_amdgcn_s_setprio(0);

        if (kt < 15) {
            if (kt < 14) {
                asm volatile("s_waitcnt vmcnt(4) lgkmcnt(0)" ::: "memory");
            } else {
                asm volatile("s_waitcnt vmcnt(0) lgkmcnt(0)" ::: "memory");
            }
            __builtin_amdgcn_sched_barrier(0);
            __builtin_amdgcn_s_barrier();
        }
        cur = nxt;
    }

    // epilogue: h = acc + b1; gelu; *W2; reduce 256 cols -> partial scores
    __syncthreads();
    float* red = (float*)smem;  // [4][64][17]
    const int hi = lane >> 4, lc = lane & 15;
    float b1v[4], w2v[4];
#pragma unroll
    for (int nf = 0; nf < 4; ++nf) {
        int c = nb * 256 + w * 64 + nf * 16 + lc;
        b1v[nf] = b1[c];
        w2v[nf] = W2[c];
    }
#pragma unroll
    for (int mf = 0; mf < 4; ++mf) {
#pragma unroll
        for (int i = 0; i < 4; ++i) {
            float s = 0.f;
#pragma unroll
            for (int nf = 0; nf < 4; ++nf) {
                float h = acc[mf][nf][i] + b1v[nf];
                s = fmaf(gelu_exact(h), w2v[nf], s);
            }
            red[(w * 64 + mf * 16 + hi * 4 + i) * 17 + lc] = s;
        }
    }
    __syncthreads();
    if (t < 64) {
        float s = 0.f;
#pragma unroll
        for (int ww = 0; ww < 4; ++ww)
#pragma unroll
            for (int c = 0; c < 16; ++c) s += red[(ww * 64 + t) * 17 + c];
        sparts[(size_t)nb * tot + m0 + t] = s;
    }
}

// ---- flag + provisional select from screen scores ----
__global__ void flag_select_kernel(const float* __restrict__ sparts, int tot,
                                   int* __restrict__ sel_buf,
                                   int* __restrict__ flag_list,
                                   int* __restrict__ counter, int N, int nseg_tot) {
    int seg = blockIdx.x * 256 + threadIdx.x;
    if (seg >= nseg_tot) return;
    int b = seg >> 5, s = seg & 31;
    size_t base = (size_t)b * N + s * SEG_LEN;
    float sc[SEG_LEN];
#pragma unroll
    for (int j = 0; j < SEG_LEN; ++j) sc[j] = sparts[base + j] + sparts[base + j + tot];
    unsigned mask = 0;
    float best9 = 0.f;
    for (int it = 0; it < QUOTA; ++it) {
        float best = 0.f; int bi = 0; bool found = false;
        for (int i = 0; i < SEG_LEN; ++i) if (!((mask >> i) & 1u)) {
            if (!found || sc[i] > best) { best = sc[i]; bi = i; found = true; }
        }
        mask |= 1u << bi;
        best9 = best;
    }
    float best10 = 0.f; bool f10 = false;
    for (int i = 0; i < SEG_LEN; ++i) if (!((mask >> i) & 1u)) {
        if (!f10 || sc[i] > best10) { best10 = sc[i]; f10 = true; }
    }
    if (best9 - best10 > GAP_THR) {
        int c = 0;
        for (int i = 0; i < SEG_LEN; ++i)
            if ((mask >> i) & 1u) sel_buf[(size_t)seg * QUOTA + (c++)] = i;
    } else {
        int p = atomicAdd(counter, 1);
        flag_list[p] = seg;
    }
}

// ---- exact recheck (fp16-split 3-pass, proven numerics) of flagged segments ----
__global__ __launch_bounds__(512, 2)
void recheck_kernel(const float* __restrict__ X, const _Float16* __restrict__ B32,
                    const float* __restrict__ b1, const float* __restrict__ W2,
                    const int* __restrict__ flag_list, const int* __restrict__ counter,
                    int* __restrict__ sel_buf, int N) {
    const int count = *counter;
    const int jb = blockIdx.x;
    if (jb * 3 >= count) return;
    __shared__ __align__(16) char smem[73728];
    const int t = threadIdx.x, w = t >> 6, lane = t & 63;

    const int r_ = t >> 3, kq8 = t & 7;
    int q = r_ / 18, rr = r_ % 18;
    if (r_ >= 54) { q = 2; rr = 0; }
    int li = jb * 3 + q; if (li >= count) li = count - 1;
    const int sg = flag_list[li];
    const float* aRow = X + ((size_t)(sg >> 5) * N + (sg & 31) * SEG_LEN + rr) * H_DIM + kq8 * 4;
    const int rg = r_ >> 5, aks = kq8 >> 2, ahi = (kq8 >> 1) & 1;
    const int aoff = (rg * 2 + aks) * 1024 + (ahi * 32 + (r_ & 31)) * 16 + (kq8 & 1) * 8;

    f32x16 acc1[2][2] = {};
    f32x16 acc2[2][2] = {};
    float4 av = *(const float4*)aRow;

    for (int kt = 0; kt < 32; ++kt) {
#pragma unroll
        for (int r8 = 0; r8 < 8; ++r8) {
            int idx = r8 * 512 + t;
            gload_lds16(B32 + (size_t)kt * 32768 + (size_t)idx * 8,
                        smem + 8192 + (size_t)idx * 16);
        }
        {
            float xs[4] = {av.x, av.y, av.z, av.w};
            half4 h0, h1;
#pragma unroll
            for (int j = 0; j < 4; ++j) {
                _Float16 a = (_Float16)xs[j];
                float r = xs[j] - (float)a;
                h0[j] = a;
                h1[j] = (_Float16)(r * 2048.0f);
            }
            *(half4*)(smem + aoff) = h0;
            *(half4*)(smem + 4096 + aoff) = h1;
        }
        int ktn = kt < 31 ? kt + 1 : 31;
        av = *(const float4*)(aRow + ktn * 32);
        asm volatile("s_waitcnt vmcnt(1) lgkmcnt(0)" ::: "memory");
        __builtin_amdgcn_sched_barrier(0);
        __builtin_amdgcn_s_barrier();

        half8 a0[4], a1[4], b0[4], b1f[4];
#pragma unroll
        for (int mf = 0; mf < 2; ++mf)
#pragma unroll
            for (int ks2 = 0; ks2 < 2; ++ks2) {
                a0[mf * 2 + ks2] = *(const half8*)(smem + (mf * 2 + ks2) * 1024 + lane * 16);
                a1[mf * 2 + ks2] = *(const half8*)(smem + 4096 + (mf * 2 + ks2) * 1024 + lane * 16);
            }
        const char* bb = smem + 8192 + (w >> 2) * 32768;
#pragma unroll
        for (int nfl = 0; nfl < 2; ++nfl)
#pragma unroll
            for (int ks2 = 0; ks2 < 2; ++ks2) {
                b0[nfl * 2 + ks2]  = *(const half8*)(bb + ks2 * 8192 + ((w & 3) * 2 + nfl) * 1024 + lane * 16);
                b1f[nfl * 2 + ks2] = *(const half8*)(bb + 16384 + ks2 * 8192 + ((w & 3) * 2 + nfl) * 1024 + lane * 16);
            }
        __builtin_amdgcn_s_setprio(1);
#pragma unroll
        for (int mf = 0; mf < 2; ++mf)
#pragma unroll
            for (int nfl = 0; nfl < 2; ++nfl)
#pragma unroll
                for (int ks2 = 0; ks2 < 2; ++ks2)
                    acc1[mf][nfl] = __builtin_amdgcn_mfma_f32_32x32x16_f16(
                        a0[mf * 2 + ks2], b0[nfl * 2 + ks2], acc1[mf][nfl], 0, 0, 0);
#pragma unroll
        for (int mf = 0; mf < 2; ++mf)
#pragma unroll
            for (int nfl = 0; nfl < 2; ++nfl)
#pragma unroll
                for (int ks2 = 0; ks2 < 2; ++ks2)
                    acc2[mf][nfl] = __builtin_amdgcn_mfma_f32_32x32x16_f16(
                        a0[mf * 2 + ks2], b1f[nfl * 2 + ks2], acc2[mf][nfl], 0, 0, 0);
#pragma unroll
        for (int mf = 0; mf < 2; ++mf)
#pragma unroll
            for (int nfl = 0; nfl < 2; ++nfl)
#pragma unroll
                for (int ks2 = 0; ks2 < 2; ++ks2)
                    acc2[mf][nfl] = __builtin_amdgcn_mfma_f32_32x32x16_f16(
                        a1[mf * 2 + ks2], b0[nfl * 2 + ks2], acc2[mf][nfl], 0, 0, 0);
        __builtin_amdgcn_s_setprio(0);
        __builtin_amdgcn_s_barrier();
    }

    __syncthreads();
    float* red = (float*)smem;                 // [8][64][33]
    float b1v[2], w2v[2];
#pragma unroll
    for (int nfl = 0; nfl < 2; ++nfl) {
        int c = (w >> 2) * 256 + ((w & 3) * 2 + nfl) * 32 + (lane & 31);
        b1v[nfl] = b1[c];
        w2v[nfl] = W2[c];
    }
#pragma unroll
    for (int mf = 0; mf < 2; ++mf)
#pragma unroll
        for (int i = 0; i < 16; ++i) {
            float s = 0.f;
#pragma unroll
            for (int nfl = 0; nfl < 2; ++nfl) {
                float h = acc1[mf][nfl][i] + acc2[mf][nfl][i] * (1.0f / 2048.0f) + b1v[nfl];
                s = fmaf(gelu_exact(h), w2v[nfl], s);
            }
            int row = mf * 32 + (i & 3) + 8 * (i >> 2) + 4 * (lane >> 5);
            red[(w * 64 + row) * 33 + (lane & 31)] = s;
        }
    __syncthreads();
    float* sx = (float*)(smem + 67584);        // [64]
    if (t < 64) {
        float s = 0.f;
        for (int ww = 0; ww < 8; ++ww)
#pragma unroll
            for (int lc = 0; lc < 32; ++lc) s += red[(ww * 64 + t) * 33 + lc];
        sx[t] = s;
    }
    __syncthreads();
    if (t < 3 && jb * 3 + t < count) {
        int sg2 = flag_list[jb * 3 + t];
        const float* sv = sx + t * SEG_LEN;
        unsigned mask = 0;
        for (int it = 0; it < QUOTA; ++it) {
            float best = 0.f; int bi = 0; bool found = false;
            for (int i = 0; i < SEG_LEN; ++i) if (!((mask >> i) & 1u)) {
                if (!found || sv[i] > best) { best = sv[i]; bi = i; found = true; }
            }
            mask |= 1u << bi;
        }
        int c = 0;
        for (int i = 0; i < SEG_LEN; ++i)
            if ((mask >> i) & 1u) sel_buf[(size_t)sg2 * QUOTA + (c++)] = i;
    }
}

// ---- final gather of selected rows ----
__global__ void gather_kernel(const float* __restrict__ X, const int* __restrict__ sel_buf,
                              float* __restrict__ out, int N) {
    const int seg = blockIdx.x, b = blockIdx.y, t = threadIdx.x;
    const int* sel = sel_buf + ((size_t)b * N_SEG + seg) * QUOTA;
    const float4* xb = (const float4*)X + ((size_t)b * N + seg * SEG_LEN) * (H_DIM / 4);
    float4* ob = (float4*)out + ((size_t)b * N_SEG * QUOTA + seg * QUOTA) * (H_DIM / 4);
#pragma unroll
    for (int j = 0; j < QUOTA; ++j) {
        int r = sel[j];
        ob[(size_t)j * (H_DIM / 4) + t] = xb[(size_t)r * (H_DIM / 4) + t];
    }
}

extern "C" void kernel_launch(void* const* d_in, const int* in_sizes, int n_in,
                              void* d_out, int out_size, void* d_ws, size_t ws_size,
                              hipStream_t stream) {
    const float* X  = (const float*)d_in[0];
    const float* W1 = (const float*)d_in[1];
    const float* b1 = (const float*)d_in[2];
    const float* W2 = (const float*)d_in[3];
    float* out = (float*)d_out;

    const int Hh = in_sizes[2];                        // 512
    const int H  = Hh * 2;                             // 1024
    const long long TOT = (long long)in_sizes[0] / H;  // 147456 tokens
    const int B = 256;
    const int N = (int)(TOT / B);                      // 576
    const int nseg_tot = B * N_SEG;                    // 8192

    char* ws = (char*)d_ws;
    _Float16* B32 = (_Float16*)(ws + 0);               // 2 MB
    _Float16* B16 = (_Float16*)(ws + 2097152);         // 1 MB
    float* sparts = (float*)(ws + 3145728);            // 2*TOT f32
    int* sel_buf  = (int*)(ws + 4325376);              // 8192*9
    int* flag_list= (int*)(ws + 4620288);              // 8192
    int* counter  = (int*)(ws + 4653056);

    hipMemsetAsync(counter, 0, 16, stream);

    hipLaunchKernelGGL(pack_w1_kernel, dim3(512), dim3(256), 0, stream, W1, B32, B16);

    hipLaunchKernelGGL(stage1_kernel, dim3((unsigned)(TOT / 64), 2), dim3(256), 0, stream,
                       X, B16, b1, W2, sparts, (int)TOT);

    hipLaunchKernelGGL(flag_select_kernel, dim3((nseg_tot + 255) / 256), dim3(256), 0, stream,
                       sparts, (int)TOT, sel_buf, flag_list, counter, N, nseg_tot);

    hipLaunchKernelGGL(recheck_kernel, dim3((nseg_tot + 2) / 3), dim3(512), 0, stream,
                       X, B32, b1, W2, flag_list, counter, sel_buf, N);

    hipLaunchKernelGGL(gather_kernel, dim3(N_SEG, B), dim3(256), 0, stream,
                       X, sel_buf, out, N);
}